// Round 1
// baseline (1301.811 us; speedup 1.0000x reference)
//
#include <hip/hip_runtime.h>
#include <stdint.h>

#define SEQ 2048
#define BATCH 2
#define NH 16
#define DKH 64
#define DM 1024
#define DFF 4096
#define MTOT (BATCH*SEQ)   // 4096 rows

typedef __attribute__((ext_vector_type(8))) short bf16x8;   // 8 bf16 in 4 VGPRs
typedef __attribute__((ext_vector_type(4))) float f32x4;

__device__ __forceinline__ unsigned short f2bf(float f) {
  union { float f; unsigned u; } c; c.f = f;
  return (unsigned short)((c.u + 0x7fffu + ((c.u >> 16) & 1u)) >> 16);  // RNE
}

// async global->LDS, 16B per lane; LDS dest must be wave-uniform base + lane*16
__device__ __forceinline__ void gload_lds16(const void* g, void* l) {
  __builtin_amdgcn_global_load_lds((__attribute__((address_space(1))) unsigned int*)g,
                                   (__attribute__((address_space(3))) unsigned int*)l,
                                   16, 0, 0);
}

// ---------------- prep kernels ----------------

__global__ __launch_bounds__(256) void conv_bf16(const float* __restrict__ X,
                                                 unsigned short* __restrict__ O, int n) {
  const int i = blockIdx.x * 256 + threadIdx.x;
  const int idx = i * 4;
  if (idx >= n) return;
  const float4 f = *(const float4*)(X + idx);
  ushort4 u; u.x = f2bf(f.x); u.y = f2bf(f.y); u.z = f2bf(f.z); u.w = f2bf(f.w);
  *(ushort4*)(O + idx) = u;
}

// W (K x N fp32, row-major) -> Wt (N x K bf16, row-major)  [B^T layout for gemm]
__global__ __launch_bounds__(256) void trans_conv(const float* __restrict__ W,
                                                  unsigned short* __restrict__ Wt,
                                                  int K, int N) {
  __shared__ float t[32][33];
  const int n0 = blockIdx.x * 32, k0 = blockIdx.y * 32;
  const int tx = threadIdx.x & 31, ty = threadIdx.x >> 5;  // 32 x 8
#pragma unroll
  for (int i = 0; i < 4; ++i)
    t[ty + i * 8][tx] = W[(long)(k0 + ty + i * 8) * N + n0 + tx];
  __syncthreads();
#pragma unroll
  for (int i = 0; i < 4; ++i)
    Wt[(long)(n0 + ty + i * 8) * K + k0 + tx] = f2bf(t[tx][ty + i * 8]);
}

// V bf16 (4096 x 1024) -> Vt[bh][64][2048] bf16 (per-head transposed)
__global__ __launch_bounds__(256) void trans_v(const unsigned short* __restrict__ V,
                                               unsigned short* __restrict__ Vt) {
  __shared__ unsigned short t[32][33];
  const int z = blockIdx.z, b = z >> 4, h = z & 15;
  const int s0 = blockIdx.x * 32, d0 = blockIdx.y * 32;
  const int tx = threadIdx.x & 31, ty = threadIdx.x >> 5;
#pragma unroll
  for (int i = 0; i < 4; ++i)
    t[ty + i * 8][tx] = V[(long)(b * SEQ + s0 + ty + i * 8) * DM + h * DKH + d0 + tx];
  __syncthreads();
#pragma unroll
  for (int i = 0; i < 4; ++i)
    Vt[((long)z * DKH + d0 + ty + i * 8) * SEQ + s0 + tx] = t[tx][ty + i * 8];
}

// ---------------- generic bf16 GEMM: C[m][n] = sum_k A[m][k] * Bt[n][k] ----------------
// EPI: 0 = bf16 store (+bias), 1 = fp32 store * scale, 2 = fp32 store + bias + resid,
//      3 = bf16 store of exact GELU(acc + bias)
template <int EPI>
__global__ __launch_bounds__(256) void gemm_bt(
    const unsigned short* __restrict__ A, const unsigned short* __restrict__ Bt,
    float* __restrict__ Cf, unsigned short* __restrict__ Cbf,
    const float* __restrict__ bias, const float* __restrict__ resid,
    int M, int N, int K, int lda, int ldb, int ldc,
    long sAb, long sAh, long sBb, long sBh, long sCb, long sCh, int H, float scale) {
  const int z = blockIdx.z;
  const int zb = z / H, zh = z % H;
  A += (long)zb * sAb + (long)zh * sAh;
  Bt += (long)zb * sBb + (long)zh * sBh;
  const long cOff = (long)zb * sCb + (long)zh * sCh;

  __shared__ unsigned short ldsA[128 * 32];
  __shared__ unsigned short ldsB[128 * 32];

  const int tid = threadIdx.x;
  const int lane = tid & 63, wave = tid >> 6;
  const int quad = lane >> 4, l16 = lane & 15;
  const int wm = (wave >> 1) * 64, wn = (wave & 1) * 64;
  const long tileM = (long)blockIdx.x * 128;
  const long tileN = (long)blockIdx.y * 128;

  const int srow = tid >> 2;          // 0..63
  const int scol = (tid & 3) * 8;     // 0,8,16,24
  const unsigned short* aSrc = A + (tileM + srow) * lda + scol;
  const unsigned short* bSrc = Bt + (tileN + srow) * ldb + scol;
  unsigned short* aDst = &ldsA[tid * 8];
  unsigned short* bDst = &ldsB[tid * 8];
  const long aRow64 = 64L * lda, bRow64 = 64L * ldb;

  f32x4 acc[4][4];
#pragma unroll
  for (int i = 0; i < 4; ++i)
#pragma unroll
    for (int j = 0; j < 4; ++j)
#pragma unroll
      for (int r = 0; r < 4; ++r) acc[i][j][r] = 0.f;

  for (int k0 = 0; k0 < K; k0 += 32) {
    __syncthreads();
    gload_lds16(aSrc + k0, aDst);
    gload_lds16(aSrc + aRow64 + k0, aDst + 2048);
    gload_lds16(bSrc + k0, bDst);
    gload_lds16(bSrc + bRow64 + k0, bDst + 2048);
    __syncthreads();

    bf16x8 aF[4], bF[4];
#pragma unroll
    for (int i = 0; i < 4; ++i)
      aF[i] = *(const bf16x8*)&ldsA[(wm + i * 16 + l16) * 32 + quad * 8];
#pragma unroll
    for (int j = 0; j < 4; ++j)
      bF[j] = *(const bf16x8*)&ldsB[(wn + j * 16 + l16) * 32 + quad * 8];
#pragma unroll
    for (int i = 0; i < 4; ++i)
#pragma unroll
      for (int j = 0; j < 4; ++j)
        acc[i][j] = __builtin_amdgcn_mfma_f32_16x16x32_bf16(aF[i], bF[j], acc[i][j], 0, 0, 0);
  }

#pragma unroll
  for (int i = 0; i < 4; ++i) {
    const long mb = tileM + wm + i * 16 + quad * 4;
#pragma unroll
    for (int j = 0; j < 4; ++j) {
      const long n = tileN + wn + j * 16 + l16;
      float bv = 0.f;
      if (EPI != 1) bv = bias[n];
#pragma unroll
      for (int r = 0; r < 4; ++r) {
        const long m = mb + r;
        const long idx = cOff + m * ldc + n;
        const float v = acc[i][j][r];
        if (EPI == 0) {
          Cbf[idx] = f2bf(v + bv);
        } else if (EPI == 1) {
          Cf[idx] = v * scale;
        } else if (EPI == 2) {
          Cf[idx] = v + bv + resid[idx];
        } else {
          const float tt = v + bv;
          Cbf[idx] = f2bf(0.5f * tt * (1.f + erff(tt * 0.70710678118654752f)));
        }
      }
    }
  }
}

// ---------------- softmax over rows of 2048 (in-place, fp32) ----------------
__global__ __launch_bounds__(256) void softmax_rows(float* __restrict__ P) {
  const long row = blockIdx.x;
  float* p = P + row * SEQ;
  const int tid = threadIdx.x;
  float4 v0 = *(const float4*)(p + tid * 4);
  float4 v1 = *(const float4*)(p + 1024 + tid * 4);
  float mx = fmaxf(fmaxf(fmaxf(v0.x, v0.y), fmaxf(v0.z, v0.w)),
                   fmaxf(fmaxf(v1.x, v1.y), fmaxf(v1.z, v1.w)));
#pragma unroll
  for (int o = 32; o > 0; o >>= 1) mx = fmaxf(mx, __shfl_xor(mx, o));
  __shared__ float rmax[4], rsum[4];
  if ((tid & 63) == 0) rmax[tid >> 6] = mx;
  __syncthreads();
  mx = fmaxf(fmaxf(rmax[0], rmax[1]), fmaxf(rmax[2], rmax[3]));
  v0.x = __expf(v0.x - mx); v0.y = __expf(v0.y - mx);
  v0.z = __expf(v0.z - mx); v0.w = __expf(v0.w - mx);
  v1.x = __expf(v1.x - mx); v1.y = __expf(v1.y - mx);
  v1.z = __expf(v1.z - mx); v1.w = __expf(v1.w - mx);
  float s = v0.x + v0.y + v0.z + v0.w + v1.x + v1.y + v1.z + v1.w;
#pragma unroll
  for (int o = 32; o > 0; o >>= 1) s += __shfl_xor(s, o);
  if ((tid & 63) == 0) rsum[tid >> 6] = s;
  __syncthreads();
  const float inv = 1.f / (rsum[0] + rsum[1] + rsum[2] + rsum[3]);
  v0.x *= inv; v0.y *= inv; v0.z *= inv; v0.w *= inv;
  v1.x *= inv; v1.y *= inv; v1.z *= inv; v1.w *= inv;
  *(float4*)(p + tid * 4) = v0;
  *(float4*)(p + 1024 + tid * 4) = v1;
}

// ---------------- ctx = attn(fp32) @ V: per-(b,h), M=2048, N=64, K=2048 ----------------
__global__ __launch_bounds__(256) void ctx_gemm(const float* __restrict__ P,
                                                const unsigned short* __restrict__ Vt,
                                                unsigned short* __restrict__ Ctx) {
  const int z = blockIdx.z, b = z >> 4, h = z & 15;
  const float* Pz = P + (long)z * SEQ * SEQ;
  const unsigned short* Vz = Vt + (long)z * DKH * SEQ;
  const long tileM = (long)blockIdx.x * 128;

  __shared__ unsigned short ldsA[128 * 32];
  __shared__ unsigned short ldsB[64 * 32];

  const int tid = threadIdx.x;
  const int lane = tid & 63, wave = tid >> 6;
  const int quad = lane >> 4, l16 = lane & 15;
  const int wm = (wave >> 1) * 64, wn = (wave & 1) * 32;

  const int srow = tid >> 2, scol = (tid & 3) * 8;
  const unsigned short* bSrc = Vz + (long)srow * SEQ + scol;

  f32x4 acc[4][2];
#pragma unroll
  for (int i = 0; i < 4; ++i)
#pragma unroll
    for (int j = 0; j < 2; ++j)
#pragma unroll
      for (int r = 0; r < 4; ++r) acc[i][j][r] = 0.f;

  for (int k0 = 0; k0 < SEQ; k0 += 32) {
    __syncthreads();
    gload_lds16(bSrc + k0, &ldsB[tid * 8]);
#pragma unroll
    for (int c = 0; c < 2; ++c) {
      const int e = tid * 8 + c * 2048;
      const int row = e >> 5, col = e & 31;
      const float4* p = (const float4*)(Pz + (tileM + row) * (long)SEQ + k0 + col);
      const float4 f0 = p[0], f1 = p[1];
      union { unsigned short us[8]; uint4 v; } t;
      t.us[0] = f2bf(f0.x); t.us[1] = f2bf(f0.y); t.us[2] = f2bf(f0.z); t.us[3] = f2bf(f0.w);
      t.us[4] = f2bf(f1.x); t.us[5] = f2bf(f1.y); t.us[6] = f2bf(f1.z); t.us[7] = f2bf(f1.w);
      *(uint4*)&ldsA[e] = t.v;
    }
    __syncthreads();
    bf16x8 aF[4], bF[2];
#pragma unroll
    for (int i = 0; i < 4; ++i)
      aF[i] = *(const bf16x8*)&ldsA[(wm + i * 16 + l16) * 32 + quad * 8];
#pragma unroll
    for (int j = 0; j < 2; ++j)
      bF[j] = *(const bf16x8*)&ldsB[(wn + j * 16 + l16) * 32 + quad * 8];
#pragma unroll
    for (int i = 0; i < 4; ++i)
#pragma unroll
      for (int j = 0; j < 2; ++j)
        acc[i][j] = __builtin_amdgcn_mfma_f32_16x16x32_bf16(aF[i], bF[j], acc[i][j], 0, 0, 0);
  }

#pragma unroll
  for (int i = 0; i < 4; ++i) {
#pragma unroll
    for (int j = 0; j < 2; ++j) {
      const int n = h * DKH + wn + j * 16 + l16;
#pragma unroll
      for (int r = 0; r < 4; ++r) {
        const long m = (long)b * SEQ + tileM + wm + i * 16 + quad * 4 + r;
        Ctx[m * DM + n] = f2bf(acc[i][j][r]);
      }
    }
  }
}

// ---------------- LayerNorm over rows of 1024 ----------------
__global__ __launch_bounds__(256) void layernorm_row(const float* __restrict__ Y,
                                                     const float* __restrict__ g,
                                                     const float* __restrict__ bb,
                                                     float* __restrict__ outF,
                                                     unsigned short* __restrict__ outBf) {
  const long row = blockIdx.x;
  const float* p = Y + row * DM;
  const int tid = threadIdx.x;
  const float4 v = *(const float4*)(p + tid * 4);
  float s = v.x + v.y + v.z + v.w;
  float ss = v.x * v.x + v.y * v.y + v.z * v.z + v.w * v.w;
#pragma unroll
  for (int o = 32; o > 0; o >>= 1) { s += __shfl_xor(s, o); ss += __shfl_xor(ss, o); }
  __shared__ float rs[4], rss[4];
  if ((tid & 63) == 0) { rs[tid >> 6] = s; rss[tid >> 6] = ss; }
  __syncthreads();
  s = rs[0] + rs[1] + rs[2] + rs[3];
  ss = rss[0] + rss[1] + rss[2] + rss[3];
  const float mu = s * (1.f / DM);
  const float var = ss * (1.f / DM) - mu * mu;
  const float rstd = rsqrtf(var + 1e-5f);
  const float4 gv = *(const float4*)(g + tid * 4);
  const float4 bv = *(const float4*)(bb + tid * 4);
  float4 o;
  o.x = (v.x - mu) * rstd * gv.x + bv.x;
  o.y = (v.y - mu) * rstd * gv.y + bv.y;
  o.z = (v.z - mu) * rstd * gv.z + bv.z;
  o.w = (v.w - mu) * rstd * gv.w + bv.w;
  *(float4*)(outF + row * DM + tid * 4) = o;
  if (outBf) {
    ushort4 u; u.x = f2bf(o.x); u.y = f2bf(o.y); u.z = f2bf(o.z); u.w = f2bf(o.w);
    *(ushort4*)(outBf + row * DM + tid * 4) = u;
  }
}

// ---------------- launch ----------------
extern "C" void kernel_launch(void* const* d_in, const int* in_sizes, int n_in,
                              void* d_out, int out_size, void* d_ws, size_t ws_size,
                              hipStream_t stream) {
  (void)in_sizes; (void)n_in; (void)out_size; (void)ws_size;
  const float* x  = (const float*)d_in[0];
  const float* Wq = (const float*)d_in[1];
  const float* bq = (const float*)d_in[2];
  const float* Wk = (const float*)d_in[3];
  const float* bk = (const float*)d_in[4];
  const float* Wv = (const float*)d_in[5];
  const float* bv = (const float*)d_in[6];
  const float* Wo = (const float*)d_in[7];
  const float* bo = (const float*)d_in[8];
  const float* g1 = (const float*)d_in[9];
  const float* b1 = (const float*)d_in[10];
  const float* W1 = (const float*)d_in[11];
  const float* bf1 = (const float*)d_in[12];
  const float* W2 = (const float*)d_in[13];
  const float* bf2 = (const float*)d_in[14];
  const float* g2 = (const float*)d_in[15];
  const float* b2 = (const float*)d_in[16];

  float* out  = (float*)d_out;
  float* attn = out + (long)MTOT * DM;   // (B,H,S,S) fp32, also used as score scratch

  // workspace layout (96 MB total, liveness-aliased)
  char* w = (char*)d_ws;
  const long MB = 1024L * 1024L;
  unsigned short* Wqt = (unsigned short*)(w + 0 * MB);    // 2 MB each
  unsigned short* Wkt = (unsigned short*)(w + 2 * MB);
  unsigned short* Wvt = (unsigned short*)(w + 4 * MB);
  unsigned short* Wot = (unsigned short*)(w + 6 * MB);
  unsigned short* W1t = (unsigned short*)(w + 8 * MB);    // 8 MB
  unsigned short* W2t = (unsigned short*)(w + 16 * MB);   // 8 MB
  unsigned short* xbf = (unsigned short*)(w + 24 * MB);   // 8 MB, reused as hbf
  unsigned short* hbf = xbf;
  unsigned short* Qbf = (unsigned short*)(w + 32 * MB);   // 8 MB ┐
  unsigned short* Kbf = (unsigned short*)(w + 40 * MB);   // 8 MB │ ffbf aliases 32..64 MB
  unsigned short* Vt  = (unsigned short*)(w + 48 * MB);   // 8 MB │
  unsigned short* Vbf = (unsigned short*)(w + 56 * MB);   // 8 MB ┘ (reused as ctxbf)
  unsigned short* ctxbf = Vbf;
  unsigned short* ffbf  = Qbf;                            // 32 MB alias (all dead by FF1)
  float* y = (float*)(w + 64 * MB);                       // 16 MB (y1/y2 shared)
  float* h = (float*)(w + 80 * MB);                       // 16 MB

  const dim3 blk(256);

  // prep
  conv_bf16<<<dim3(MTOT * DM / 1024), blk, 0, stream>>>(x, xbf, MTOT * DM);
  trans_conv<<<dim3(DM / 32, DM / 32), blk, 0, stream>>>(Wq, Wqt, DM, DM);
  trans_conv<<<dim3(DM / 32, DM / 32), blk, 0, stream>>>(Wk, Wkt, DM, DM);
  trans_conv<<<dim3(DM / 32, DM / 32), blk, 0, stream>>>(Wv, Wvt, DM, DM);
  trans_conv<<<dim3(DM / 32, DM / 32), blk, 0, stream>>>(Wo, Wot, DM, DM);
  trans_conv<<<dim3(DFF / 32, DM / 32), blk, 0, stream>>>(W1, W1t, DM, DFF);
  trans_conv<<<dim3(DM / 32, DFF / 32), blk, 0, stream>>>(W2, W2t, DFF, DM);

  // QKV projections (bf16 out)
  gemm_bt<0><<<dim3(MTOT / 128, DM / 128, 1), blk, 0, stream>>>(
      xbf, Wqt, nullptr, Qbf, bq, nullptr, MTOT, DM, DM, DM, DM, DM,
      0, 0, 0, 0, 0, 0, 1, 1.f);
  gemm_bt<0><<<dim3(MTOT / 128, DM / 128, 1), blk, 0, stream>>>(
      xbf, Wkt, nullptr, Kbf, bk, nullptr, MTOT, DM, DM, DM, DM, DM,
      0, 0, 0, 0, 0, 0, 1, 1.f);
  gemm_bt<0><<<dim3(MTOT / 128, DM / 128, 1), blk, 0, stream>>>(
      xbf, Wvt, nullptr, Vbf, bv, nullptr, MTOT, DM, DM, DM, DM, DM,
      0, 0, 0, 0, 0, 0, 1, 1.f);
  trans_v<<<dim3(SEQ / 32, DKH / 32, BATCH * NH), blk, 0, stream>>>(Vbf, Vt);

  // scores = Q K^T / 8 (batched over 32 (b,h)), fp32 into attn region
  gemm_bt<1><<<dim3(SEQ / 128, SEQ / 128, BATCH * NH), blk, 0, stream>>>(
      Qbf, Kbf, attn, nullptr, nullptr, nullptr, SEQ, SEQ, DKH, DM, DM, SEQ,
      (long)SEQ * DM, 64L, (long)SEQ * DM, 64L,
      (long)NH * SEQ * SEQ, (long)SEQ * SEQ, NH, 0.125f);

  softmax_rows<<<dim3(BATCH * NH * SEQ), blk, 0, stream>>>(attn);

  // ctx = attn @ V  -> bf16 (4096 x 1024)
  ctx_gemm<<<dim3(SEQ / 128, 1, BATCH * NH), blk, 0, stream>>>(attn, Vt, ctxbf);

  // attn_out = ctx @ Wo + bo + x  (fp32)
  gemm_bt<2><<<dim3(MTOT / 128, DM / 128, 1), blk, 0, stream>>>(
      ctxbf, Wot, y, nullptr, bo, x, MTOT, DM, DM, DM, DM, DM,
      0, 0, 0, 0, 0, 0, 1, 1.f);
  layernorm_row<<<dim3(MTOT), blk, 0, stream>>>(y, g1, b1, h, hbf);

  // FFN
  gemm_bt<3><<<dim3(MTOT / 128, DFF / 128, 1), blk, 0, stream>>>(
      hbf, W1t, nullptr, ffbf, bf1, nullptr, MTOT, DFF, DM, DM, DM, DFF,
      0, 0, 0, 0, 0, 0, 1, 1.f);
  gemm_bt<2><<<dim3(MTOT / 128, DM / 128, 1), blk, 0, stream>>>(
      ffbf, W2t, y, nullptr, bf2, h, MTOT, DM, DFF, DFF, DFF, DM,
      0, 0, 0, 0, 0, 0, 1, 1.f);
  layernorm_row<<<dim3(MTOT), blk, 0, stream>>>(y, g2, b2, out, nullptr);
}

// Round 2
// 1086.800 us; speedup vs baseline: 1.1978x; 1.1978x over previous
//
#include <hip/hip_runtime.h>
#include <stdint.h>

#define SEQ 2048
#define BATCH 2
#define NH 16
#define DKH 64
#define DM 1024
#define DFF 4096
#define MTOT (BATCH*SEQ)   // 4096 rows

typedef __attribute__((ext_vector_type(8))) short bf16x8;   // 8 bf16 in 4 VGPRs
typedef __attribute__((ext_vector_type(4))) float f32x4;
typedef unsigned short ushort_t;

__device__ __forceinline__ unsigned short f2bf(float f) {
  union { float f; unsigned u; } c; c.f = f;
  return (unsigned short)((c.u + 0x7fffu + ((c.u >> 16) & 1u)) >> 16);  // RNE
}

// async global->LDS, 16B per lane; LDS dest must be wave-uniform base + lane*16
__device__ __forceinline__ void gload_lds16(const void* g, void* l) {
  __builtin_amdgcn_global_load_lds((__attribute__((address_space(1))) unsigned int*)g,
                                   (__attribute__((address_space(3))) unsigned int*)l,
                                   16, 0, 0);
}

// ---------------- prep kernels ----------------

__global__ __launch_bounds__(256) void conv_bf16(const float* __restrict__ X,
                                                 unsigned short* __restrict__ O, int n) {
  const int i = blockIdx.x * 256 + threadIdx.x;
  const int idx = i * 4;
  if (idx >= n) return;
  const float4 f = *(const float4*)(X + idx);
  ushort4 u; u.x = f2bf(f.x); u.y = f2bf(f.y); u.z = f2bf(f.z); u.w = f2bf(f.w);
  *(ushort4*)(O + idx) = u;
}

// W (K x N fp32, row-major) -> Wt (N x K bf16, row-major)  [B^T layout for gemm]
__global__ __launch_bounds__(256) void trans_conv(const float* __restrict__ W,
                                                  unsigned short* __restrict__ Wt,
                                                  int K, int N) {
  __shared__ float t[32][33];
  const int n0 = blockIdx.x * 32, k0 = blockIdx.y * 32;
  const int tx = threadIdx.x & 31, ty = threadIdx.x >> 5;  // 32 x 8
#pragma unroll
  for (int i = 0; i < 4; ++i)
    t[ty + i * 8][tx] = W[(long)(k0 + ty + i * 8) * N + n0 + tx];
  __syncthreads();
#pragma unroll
  for (int i = 0; i < 4; ++i)
    Wt[(long)(n0 + ty + i * 8) * K + k0 + tx] = f2bf(t[tx][ty + i * 8]);
}

// V bf16 (4096 x 1024) -> Vt[bh][64][2048] bf16 (per-head transposed)
__global__ __launch_bounds__(256) void trans_v(const unsigned short* __restrict__ V,
                                               unsigned short* __restrict__ Vt) {
  __shared__ unsigned short t[32][33];
  const int z = blockIdx.z, b = z >> 4, h = z & 15;
  const int s0 = blockIdx.x * 32, d0 = blockIdx.y * 32;
  const int tx = threadIdx.x & 31, ty = threadIdx.x >> 5;
#pragma unroll
  for (int i = 0; i < 4; ++i)
    t[ty + i * 8][tx] = V[(long)(b * SEQ + s0 + ty + i * 8) * DM + h * DKH + d0 + tx];
  __syncthreads();
#pragma unroll
  for (int i = 0; i < 4; ++i)
    Vt[((long)z * DKH + d0 + ty + i * 8) * SEQ + s0 + tx] = t[tx][ty + i * 8];
}

// ---------------- generic bf16 GEMM: C[m][n] = sum_k A[m][k] * Bt[n][k] ----------------
// EPI: 0 = bf16 store (+bias), 2 = fp32 store + bias + resid,
//      3 = bf16 store of exact GELU(acc + bias)
template <int EPI>
__global__ __launch_bounds__(256) void gemm_bt(
    const unsigned short* __restrict__ A, const unsigned short* __restrict__ Bt,
    float* __restrict__ Cf, unsigned short* __restrict__ Cbf,
    const float* __restrict__ bias, const float* __restrict__ resid,
    int M, int N, int K, int lda, int ldb, int ldc) {
  __shared__ unsigned short ldsA[128 * 32];
  __shared__ unsigned short ldsB[128 * 32];

  const int tid = threadIdx.x;
  const int lane = tid & 63, wave = tid >> 6;
  const int quad = lane >> 4, l16 = lane & 15;
  const int wm = (wave >> 1) * 64, wn = (wave & 1) * 64;
  const long tileM = (long)blockIdx.x * 128;
  const long tileN = (long)blockIdx.y * 128;

  const int srow = tid >> 2;          // 0..63
  const int scol = (tid & 3) * 8;     // 0,8,16,24
  const unsigned short* aSrc = A + (tileM + srow) * lda + scol;
  const unsigned short* bSrc = Bt + (tileN + srow) * ldb + scol;
  unsigned short* aDst = &ldsA[tid * 8];
  unsigned short* bDst = &ldsB[tid * 8];
  const long aRow64 = 64L * lda, bRow64 = 64L * ldb;

  f32x4 acc[4][4];
#pragma unroll
  for (int i = 0; i < 4; ++i)
#pragma unroll
    for (int j = 0; j < 4; ++j)
#pragma unroll
      for (int r = 0; r < 4; ++r) acc[i][j][r] = 0.f;

  for (int k0 = 0; k0 < K; k0 += 32) {
    __syncthreads();
    gload_lds16(aSrc + k0, aDst);
    gload_lds16(aSrc + aRow64 + k0, aDst + 2048);
    gload_lds16(bSrc + k0, bDst);
    gload_lds16(bSrc + bRow64 + k0, bDst + 2048);
    __syncthreads();

    bf16x8 aF[4], bF[4];
#pragma unroll
    for (int i = 0; i < 4; ++i)
      aF[i] = *(const bf16x8*)&ldsA[(wm + i * 16 + l16) * 32 + quad * 8];
#pragma unroll
    for (int j = 0; j < 4; ++j)
      bF[j] = *(const bf16x8*)&ldsB[(wn + j * 16 + l16) * 32 + quad * 8];
#pragma unroll
    for (int i = 0; i < 4; ++i)
#pragma unroll
      for (int j = 0; j < 4; ++j)
        acc[i][j] = __builtin_amdgcn_mfma_f32_16x16x32_bf16(aF[i], bF[j], acc[i][j], 0, 0, 0);
  }

#pragma unroll
  for (int i = 0; i < 4; ++i) {
    const long mb = tileM + wm + i * 16 + quad * 4;
#pragma unroll
    for (int j = 0; j < 4; ++j) {
      const long n = tileN + wn + j * 16 + l16;
      const float bv = bias[n];
#pragma unroll
      for (int r = 0; r < 4; ++r) {
        const long m = mb + r;
        const long idx = m * ldc + n;
        const float v = acc[i][j][r];
        if (EPI == 0) {
          Cbf[idx] = f2bf(v + bv);
        } else if (EPI == 2) {
          Cf[idx] = v + bv + resid[idx];
        } else {
          const float tt = v + bv;
          Cbf[idx] = f2bf(0.5f * tt * (1.f + erff(tt * 0.70710678118654752f)));
        }
      }
    }
  }
}

// ---------------- attention pass A: per-row max & sumexp of S = QK^T/8 ----------------
// grid (SEQ/128, 1, BATCH*NH), block 256
__global__ __launch_bounds__(256) void attn_stats(const unsigned short* __restrict__ Qbf,
                                                  const unsigned short* __restrict__ Kbf,
                                                  float2* __restrict__ stats) {
  const int z = blockIdx.z, b = z >> 4, h = z & 15;
  const int m0 = blockIdx.x * 128;

  __shared__ unsigned short ldsQ[2 * 128 * 32];  // [slab][row][32]
  __shared__ unsigned short ldsK[2 * 128 * 32];
  __shared__ float2 sm[4][64];

  const int tid = threadIdx.x;
  const int lane = tid & 63, wave = tid >> 6;
  const int quad = lane >> 4, l16 = lane & 15;
  const int wm = (wave >> 1) * 64, wn = (wave & 1) * 64;

  // stage Q strip once: 128 rows x 64 cols -> [2][128][32]
  const unsigned short* Qbase = Qbf + ((long)(b * SEQ + m0)) * DM + h * DKH;
#pragma unroll
  for (int it = 0; it < 4; ++it) {
    const int c = it * 256 + tid;
    const int slab = c >> 9, row = (c >> 2) & 127, q = c & 3;
    gload_lds16(Qbase + (long)row * DM + slab * 32 + q * 8, &ldsQ[c * 8]);
  }

  float rm[4][4], rl[4][4];
#pragma unroll
  for (int i = 0; i < 4; ++i)
#pragma unroll
    for (int r = 0; r < 4; ++r) { rm[i][r] = -1e30f; rl[i][r] = 0.f; }

  for (int n = 0; n < 16; ++n) {
    __syncthreads();
    const unsigned short* Kbase = Kbf + ((long)(b * SEQ + n * 128)) * DM + h * DKH;
#pragma unroll
    for (int it = 0; it < 4; ++it) {
      const int c = it * 256 + tid;
      const int slab = c >> 9, row = (c >> 2) & 127, q = c & 3;
      gload_lds16(Kbase + (long)row * DM + slab * 32 + q * 8, &ldsK[c * 8]);
    }
    __syncthreads();

    f32x4 acc[4][4];
#pragma unroll
    for (int i = 0; i < 4; ++i)
#pragma unroll
      for (int j = 0; j < 4; ++j)
#pragma unroll
        for (int r = 0; r < 4; ++r) acc[i][j][r] = 0.f;

#pragma unroll
    for (int s = 0; s < 2; ++s) {
      bf16x8 aF[4], bF[4];
#pragma unroll
      for (int i = 0; i < 4; ++i)
        aF[i] = *(const bf16x8*)&ldsQ[(s * 128 + wm + i * 16 + l16) * 32 + quad * 8];
#pragma unroll
      for (int j = 0; j < 4; ++j)
        bF[j] = *(const bf16x8*)&ldsK[(s * 128 + wn + j * 16 + l16) * 32 + quad * 8];
#pragma unroll
      for (int i = 0; i < 4; ++i)
#pragma unroll
        for (int j = 0; j < 4; ++j)
          acc[i][j] = __builtin_amdgcn_mfma_f32_16x16x32_bf16(aF[i], bF[j], acc[i][j], 0, 0, 0);
    }

    // online softmax update per row (i,r); row's 64 cols live in 4 j-regs x 16 lanes
#pragma unroll
    for (int i = 0; i < 4; ++i)
#pragma unroll
      for (int r = 0; r < 4; ++r) {
        float v0 = acc[i][0][r] * 0.125f, v1 = acc[i][1][r] * 0.125f;
        float v2 = acc[i][2][r] * 0.125f, v3 = acc[i][3][r] * 0.125f;
        float tm = fmaxf(fmaxf(v0, v1), fmaxf(v2, v3));
#pragma unroll
        for (int o = 1; o < 16; o <<= 1) tm = fmaxf(tm, __shfl_xor(tm, o));
        const float mnew = fmaxf(rm[i][r], tm);
        float s4 = __expf(v0 - mnew) + __expf(v1 - mnew) +
                   __expf(v2 - mnew) + __expf(v3 - mnew);
#pragma unroll
        for (int o = 1; o < 16; o <<= 1) s4 += __shfl_xor(s4, o);
        rl[i][r] = rl[i][r] * __expf(rm[i][r] - mnew) + s4;
        rm[i][r] = mnew;
      }
  }

  if (l16 == 0) {
#pragma unroll
    for (int i = 0; i < 4; ++i)
#pragma unroll
      for (int r = 0; r < 4; ++r)
        sm[wave][i * 16 + quad * 4 + r] = make_float2(rm[i][r], rl[i][r]);
  }
  __syncthreads();
  if (tid < 128) {
    const int row = tid, g = row >> 6;
    const float2 a = sm[g * 2 + 0][row & 63];
    const float2 bb = sm[g * 2 + 1][row & 63];
    const float M = fmaxf(a.x, bb.x);
    const float Z = a.y * __expf(a.x - M) + bb.y * __expf(bb.x - M);
    stats[(long)z * SEQ + m0 + row] = make_float2(M, 1.f / Z);
  }
}

// ---------------- attention pass B: attn = softmax(S) written + ctx = attn@V ----------------
// grid (SEQ/128, 1, BATCH*NH), block 256; LDS 80KB -> 2 blocks/CU
__global__ __launch_bounds__(256) void attn_fused(const unsigned short* __restrict__ Qbf,
                                                  const unsigned short* __restrict__ Kbf,
                                                  const unsigned short* __restrict__ Vt,
                                                  const float2* __restrict__ stats,
                                                  float* __restrict__ attn,
                                                  unsigned short* __restrict__ Ctx) {
  const int z = blockIdx.z, b = z >> 4, h = z & 15;
  const int m0 = blockIdx.x * 128;

  __shared__ unsigned short ldsQ[2 * 128 * 32];  // 16 KB
  __shared__ unsigned short ldsK[2 * 128 * 32];  // 16 KB
  __shared__ unsigned short ldsV[4 * 64 * 32];   // 16 KB  [slab][d][32]
  __shared__ unsigned short ldsP[4 * 128 * 32];  // 32 KB  [slab][row][32]

  const int tid = threadIdx.x;
  const int lane = tid & 63, wave = tid >> 6;
  const int quad = lane >> 4, l16 = lane & 15;
  const int wm = (wave >> 1) * 64, wn = (wave & 1) * 64;    // S-gemm quadrant
  const int wm2 = (wave >> 1) * 64, wn2 = (wave & 1) * 32;  // PV-gemm quadrant

  // stage Q strip once
  const unsigned short* Qbase = Qbf + ((long)(b * SEQ + m0)) * DM + h * DKH;
#pragma unroll
  for (int it = 0; it < 4; ++it) {
    const int c = it * 256 + tid;
    const int slab = c >> 9, row = (c >> 2) & 127, q = c & 3;
    gload_lds16(Qbase + (long)row * DM + slab * 32 + q * 8, &ldsQ[c * 8]);
  }

  // per-row softmax stats for this wave's S rows
  float sM[4][4], sI[4][4];
#pragma unroll
  for (int i = 0; i < 4; ++i)
#pragma unroll
    for (int r = 0; r < 4; ++r) {
      const float2 st = stats[(long)z * SEQ + m0 + wm + i * 16 + quad * 4 + r];
      sM[i][r] = st.x; sI[i][r] = st.y;
    }

  f32x4 acc_o[4][2];
#pragma unroll
  for (int i = 0; i < 4; ++i)
#pragma unroll
    for (int j = 0; j < 2; ++j)
#pragma unroll
      for (int r = 0; r < 4; ++r) acc_o[i][j][r] = 0.f;

  for (int n = 0; n < 16; ++n) {
    __syncthreads();  // prior PV reads of ldsV/ldsP done; safe to restage
    const unsigned short* Kbase = Kbf + ((long)(b * SEQ + n * 128)) * DM + h * DKH;
#pragma unroll
    for (int it = 0; it < 4; ++it) {
      const int c = it * 256 + tid;
      const int slab = c >> 9, row = (c >> 2) & 127, q = c & 3;
      gload_lds16(Kbase + (long)row * DM + slab * 32 + q * 8, &ldsK[c * 8]);
    }
    const unsigned short* Vbase = Vt + (long)z * DKH * SEQ + n * 128;
#pragma unroll
    for (int it = 0; it < 4; ++it) {
      const int c = it * 256 + tid;
      const int slab = c >> 8, row = (c >> 2) & 63, q = c & 3;
      gload_lds16(Vbase + (long)row * SEQ + slab * 32 + q * 8, &ldsV[c * 8]);
    }
    __syncthreads();

    // S = Q K^T
    f32x4 acc[4][4];
#pragma unroll
    for (int i = 0; i < 4; ++i)
#pragma unroll
      for (int j = 0; j < 4; ++j)
#pragma unroll
        for (int r = 0; r < 4; ++r) acc[i][j][r] = 0.f;
#pragma unroll
    for (int s = 0; s < 2; ++s) {
      bf16x8 aF[4], bF[4];
#pragma unroll
      for (int i = 0; i < 4; ++i)
        aF[i] = *(const bf16x8*)&ldsQ[(s * 128 + wm + i * 16 + l16) * 32 + quad * 8];
#pragma unroll
      for (int j = 0; j < 4; ++j)
        bF[j] = *(const bf16x8*)&ldsK[(s * 128 + wn + j * 16 + l16) * 32 + quad * 8];
#pragma unroll
      for (int i = 0; i < 4; ++i)
#pragma unroll
        for (int j = 0; j < 4; ++j)
          acc[i][j] = __builtin_amdgcn_mfma_f32_16x16x32_bf16(aF[i], bF[j], acc[i][j], 0, 0, 0);
    }

    // P = exp(S/8 - M) * invZ : store fp32 attn (mandatory) + bf16 into ldsP (A-layout rows)
    float* attnBase = attn + (long)z * SEQ * SEQ + (long)m0 * SEQ + n * 128;
#pragma unroll
    for (int i = 0; i < 4; ++i)
#pragma unroll
      for (int r = 0; r < 4; ++r) {
        const int rowl = wm + i * 16 + quad * 4 + r;
        const float M = sM[i][r], I = sI[i][r];
#pragma unroll
        for (int j = 0; j < 4; ++j) {
          const int col = wn + j * 16 + l16;
          const float p = __expf(acc[i][j][r] * 0.125f - M) * I;
          attnBase[(long)rowl * SEQ + col] = p;
          ldsP[((col >> 5) * 128 + rowl) * 32 + (col & 31)] = f2bf(p);
        }
      }
    __syncthreads();

    // ctx += P @ V   (M=128, N=64, K=128)
#pragma unroll
    for (int slab = 0; slab < 4; ++slab) {
      bf16x8 aF[4], bF[2];
#pragma unroll
      for (int i = 0; i < 4; ++i)
        aF[i] = *(const bf16x8*)&ldsP[(slab * 128 + wm2 + i * 16 + l16) * 32 + quad * 8];
#pragma unroll
      for (int j = 0; j < 2; ++j)
        bF[j] = *(const bf16x8*)&ldsV[(slab * 64 + wn2 + j * 16 + l16) * 32 + quad * 8];
#pragma unroll
      for (int i = 0; i < 4; ++i)
#pragma unroll
        for (int j = 0; j < 2; ++j)
          acc_o[i][j] = __builtin_amdgcn_mfma_f32_16x16x32_bf16(aF[i], bF[j], acc_o[i][j], 0, 0, 0);
    }
  }

  // epilogue: ctx bf16 (rows interleaved back to [B*S][DM])
#pragma unroll
  for (int i = 0; i < 4; ++i)
#pragma unroll
    for (int j = 0; j < 2; ++j) {
      const int d = h * DKH + wn2 + j * 16 + l16;
#pragma unroll
      for (int r = 0; r < 4; ++r) {
        const long m = (long)b * SEQ + m0 + wm2 + i * 16 + quad * 4 + r;
        Ctx[m * DM + d] = f2bf(acc_o[i][j][r]);
      }
    }
}

// ---------------- LayerNorm over rows of 1024 ----------------
__global__ __launch_bounds__(256) void layernorm_row(const float* __restrict__ Y,
                                                     const float* __restrict__ g,
                                                     const float* __restrict__ bb,
                                                     float* __restrict__ outF,
                                                     unsigned short* __restrict__ outBf) {
  const long row = blockIdx.x;
  const float* p = Y + row * DM;
  const int tid = threadIdx.x;
  const float4 v = *(const float4*)(p + tid * 4);
  float s = v.x + v.y + v.z + v.w;
  float ss = v.x * v.x + v.y * v.y + v.z * v.z + v.w * v.w;
#pragma unroll
  for (int o = 32; o > 0; o >>= 1) { s += __shfl_xor(s, o); ss += __shfl_xor(ss, o); }
  __shared__ float rs[4], rss[4];
  if ((tid & 63) == 0) { rs[tid >> 6] = s; rss[tid >> 6] = ss; }
  __syncthreads();
  s = rs[0] + rs[1] + rs[2] + rs[3];
  ss = rss[0] + rss[1] + rss[2] + rss[3];
  const float mu = s * (1.f / DM);
  const float var = ss * (1.f / DM) - mu * mu;
  const float rstd = rsqrtf(var + 1e-5f);
  const float4 gv = *(const float4*)(g + tid * 4);
  const float4 bv = *(const float4*)(bb + tid * 4);
  float4 o;
  o.x = (v.x - mu) * rstd * gv.x + bv.x;
  o.y = (v.y - mu) * rstd * gv.y + bv.y;
  o.z = (v.z - mu) * rstd * gv.z + bv.z;
  o.w = (v.w - mu) * rstd * gv.w + bv.w;
  *(float4*)(outF + row * DM + tid * 4) = o;
  if (outBf) {
    ushort4 u; u.x = f2bf(o.x); u.y = f2bf(o.y); u.z = f2bf(o.z); u.w = f2bf(o.w);
    *(ushort4*)(outBf + row * DM + tid * 4) = u;
  }
}

// ---------------- launch ----------------
extern "C" void kernel_launch(void* const* d_in, const int* in_sizes, int n_in,
                              void* d_out, int out_size, void* d_ws, size_t ws_size,
                              hipStream_t stream) {
  (void)in_sizes; (void)n_in; (void)out_size; (void)ws_size;
  const float* x  = (const float*)d_in[0];
  const float* Wq = (const float*)d_in[1];
  const float* bq = (const float*)d_in[2];
  const float* Wk = (const float*)d_in[3];
  const float* bk = (const float*)d_in[4];
  const float* Wv = (const float*)d_in[5];
  const float* bv = (const float*)d_in[6];
  const float* Wo = (const float*)d_in[7];
  const float* bo = (const float*)d_in[8];
  const float* g1 = (const float*)d_in[9];
  const float* b1 = (const float*)d_in[10];
  const float* W1 = (const float*)d_in[11];
  const float* bf1 = (const float*)d_in[12];
  const float* W2 = (const float*)d_in[13];
  const float* bf2 = (const float*)d_in[14];
  const float* g2 = (const float*)d_in[15];
  const float* b2 = (const float*)d_in[16];

  float* out  = (float*)d_out;
  float* attn = out + (long)MTOT * DM;   // (B,H,S,S) fp32 — written once, by attn_fused

  // workspace layout (liveness-aliased)
  char* w = (char*)d_ws;
  const long MB = 1024L * 1024L;
  unsigned short* Wqt = (unsigned short*)(w + 0 * MB);    // 2 MB each
  unsigned short* Wkt = (unsigned short*)(w + 2 * MB);
  unsigned short* Wvt = (unsigned short*)(w + 4 * MB);
  unsigned short* Wot = (unsigned short*)(w + 6 * MB);
  unsigned short* W1t = (unsigned short*)(w + 8 * MB);    // 8 MB
  unsigned short* W2t = (unsigned short*)(w + 16 * MB);   // 8 MB
  unsigned short* xbf = (unsigned short*)(w + 24 * MB);   // 8 MB, reused as hbf
  unsigned short* hbf = xbf;
  unsigned short* Qbf = (unsigned short*)(w + 32 * MB);   // 8 MB ┐
  unsigned short* Kbf = (unsigned short*)(w + 40 * MB);   // 8 MB │ ffbf aliases 32..64 MB
  unsigned short* Vt  = (unsigned short*)(w + 48 * MB);   // 8 MB │
  unsigned short* Vbf = (unsigned short*)(w + 56 * MB);   // 8 MB ┘ (reused as ctxbf)
  unsigned short* ctxbf = Vbf;
  unsigned short* ffbf  = Qbf;                            // 32 MB alias (dead by FF1)
  float* y = (float*)(w + 64 * MB);                       // 16 MB (first written by Wo-gemm)
  float2* stats = (float2*)(w + 64 * MB);                 // 512 KB, dead before y is written
  float* h = (float*)(w + 80 * MB);                       // 16 MB

  const dim3 blk(256);

  // prep
  conv_bf16<<<dim3(MTOT * DM / 1024), blk, 0, stream>>>(x, xbf, MTOT * DM);
  trans_conv<<<dim3(DM / 32, DM / 32), blk, 0, stream>>>(Wq, Wqt, DM, DM);
  trans_conv<<<dim3(DM / 32, DM / 32), blk, 0, stream>>>(Wk, Wkt, DM, DM);
  trans_conv<<<dim3(DM / 32, DM / 32), blk, 0, stream>>>(Wv, Wvt, DM, DM);
  trans_conv<<<dim3(DM / 32, DM / 32), blk, 0, stream>>>(Wo, Wot, DM, DM);
  trans_conv<<<dim3(DFF / 32, DM / 32), blk, 0, stream>>>(W1, W1t, DM, DFF);
  trans_conv<<<dim3(DM / 32, DFF / 32), blk, 0, stream>>>(W2, W2t, DFF, DM);

  // QKV projections (bf16 out)
  gemm_bt<0><<<dim3(MTOT / 128, DM / 128), blk, 0, stream>>>(
      xbf, Wqt, nullptr, Qbf, bq, nullptr, MTOT, DM, DM, DM, DM, DM);
  gemm_bt<0><<<dim3(MTOT / 128, DM / 128), blk, 0, stream>>>(
      xbf, Wkt, nullptr, Kbf, bk, nullptr, MTOT, DM, DM, DM, DM, DM);
  gemm_bt<0><<<dim3(MTOT / 128, DM / 128), blk, 0, stream>>>(
      xbf, Wvt, nullptr, Vbf, bv, nullptr, MTOT, DM, DM, DM, DM, DM);
  trans_v<<<dim3(SEQ / 32, DKH / 32, BATCH * NH), blk, 0, stream>>>(Vbf, Vt);

  // fused attention
  attn_stats<<<dim3(SEQ / 128, 1, BATCH * NH), blk, 0, stream>>>(Qbf, Kbf, stats);
  attn_fused<<<dim3(SEQ / 128, 1, BATCH * NH), blk, 0, stream>>>(Qbf, Kbf, Vt, stats,
                                                                 attn, ctxbf);

  // attn_out = ctx @ Wo + bo + x  (fp32)
  gemm_bt<2><<<dim3(MTOT / 128, DM / 128), blk, 0, stream>>>(
      ctxbf, Wot, y, nullptr, bo, x, MTOT, DM, DM, DM, DM, DM);
  layernorm_row<<<dim3(MTOT), blk, 0, stream>>>(y, g1, b1, h, hbf);

  // FFN
  gemm_bt<3><<<dim3(MTOT / 128, DFF / 128), blk, 0, stream>>>(
      hbf, W1t, nullptr, ffbf, bf1, nullptr, MTOT, DFF, DM, DM, DM, DFF);
  gemm_bt<2><<<dim3(MTOT / 128, DM / 128), blk, 0, stream>>>(
      ffbf, W2t, y, nullptr, bf2, h, MTOT, DM, DFF, DFF, DFF, DM);
  layernorm_row<<<dim3(MTOT), blk, 0, stream>>>(y, g2, b2, out, nullptr);
}